// Round 11
// baseline (20.433 us; speedup 1.0000x reference)
//
#include <hip/hip_runtime.h>
#include <math.h>

#define SEQ   32768
#define DENC  200
#define NH    8192

#define K1B       128
#define K1T       512
#define K1ROWS_PB (NH / K1B)             // 64 rows per block
#define K1ROWS_PG (K1ROWS_PB / 2)        // 32 rows per 256-thread group

#define K2B    512
#define K2T    512                       // 8 waves
#define K2ROWS (SEQ / K2B)               // 64 rows per block
#define RPW    8                         // rows per wave

#define K3B    (SEQ / 256)               // 128

// ws layout: float ws_v[K1B*DENC] (plain-stored banks); double ws_p[SEQ];
// double ws_sum[K2B]. Everything fully rewritten every launch; no zeroing,
// no atomics, no cross-block communication inside a kernel (G16).

__device__ __forceinline__ double wave_sum_d(double x) {
    #pragma unroll
    for (int off = 32; off; off >>= 1) x += __shfl_xor(x, off, 64);
    return x;
}
__device__ __forceinline__ float wave_sum(float x) {
    #pragma unroll
    for (int off = 32; off; off >>= 1) x += __shfl_xor(x, off, 64);
    return x;
}

// ---- K1: 128 plain-stored v-partial banks (no atomics, no memset).
__global__ __launch_bounds__(K1T) void k1_proj(const float* __restrict__ W,
                                               const float* __restrict__ hidden,
                                               float* __restrict__ ws_v) {
    __shared__ float part[2][DENC];
    const int t = threadIdx.x, b = blockIdx.x;
    const int g = t >> 8, lt = t & 255;
    const int h0 = b * K1ROWS_PB + g * K1ROWS_PG;

    if (lt < DENC) {
        float acc = 0.f;
        #pragma unroll 8
        for (int i = 0; i < K1ROWS_PG; ++i)
            acc = fmaf(W[(size_t)(h0 + i) * DENC + lt], hidden[h0 + i], acc);
        part[g][lt] = acc;
    }
    __syncthreads();
    if (t < DENC)
        ws_v[b * DENC + t] = part[0][t] + part[1][t];
}

// ---- K2: energies from register-preloaded enc rows; v reduced from 128 banks
// (round-8 single-group form); exp via v_exp_f32 + exponent-bit double scale.
__global__ __launch_bounds__(K2T) void k2_energy(const float* __restrict__ enc,
                                                 const float* __restrict__ ws_v,
                                                 double* __restrict__ ws_p,
                                                 double* __restrict__ ws_sum) {
    __shared__ float  v_lds[DENC];
    __shared__ double s_lds[K2T / 64];
    const int t = threadIdx.x, b = blockIdx.x;
    const int lane = t & 63, wid = t >> 6;
    const bool act = (lane < 50);

    // enc loads first: they are the long pole
    const int s0 = b * K2ROWS + wid * RPW;
    const float* ebase = enc + (size_t)s0 * DENC + lane * 4;
    float4 q0 = *(const float4*)(act ? ebase + 0*DENC : enc);
    float4 q1 = *(const float4*)(act ? ebase + 1*DENC : enc);
    float4 q2 = *(const float4*)(act ? ebase + 2*DENC : enc);
    float4 q3 = *(const float4*)(act ? ebase + 3*DENC : enc);
    float4 q4 = *(const float4*)(act ? ebase + 4*DENC : enc);
    float4 q5 = *(const float4*)(act ? ebase + 5*DENC : enc);
    float4 q6 = *(const float4*)(act ? ebase + 6*DENC : enc);
    float4 q7 = *(const float4*)(act ? ebase + 7*DENC : enc);

    // v from 128 float banks: 100KB per block, L2-resident, coalesced
    if (t < DENC) {
        float a0 = 0.f, a1 = 0.f, a2 = 0.f, a3 = 0.f;
        const float* p = ws_v + t;
        #pragma unroll 4
        for (int k = 0; k < K1B; k += 4) {
            a0 += p[(size_t)(k + 0) * DENC];
            a1 += p[(size_t)(k + 1) * DENC];
            a2 += p[(size_t)(k + 2) * DENC];
            a3 += p[(size_t)(k + 3) * DENC];
        }
        v_lds[t] = (a0 + a1) + (a2 + a3);
    }
    __syncthreads();

    float4 v4 = make_float4(0.f, 0.f, 0.f, 0.f);
    if (act) v4 = *(const float4*)(v_lds + lane * 4);

    float e0,e1,e2,e3,e4,e5,e6,e7;
    #define DOT(qi, ei) { \
        float d = act ? (qi.x*v4.x + qi.y*v4.y + qi.z*v4.z + qi.w*v4.w) : 0.f; \
        ei = wave_sum(d); }
    DOT(q0,e0) DOT(q1,e1) DOT(q2,e2) DOT(q3,e3)
    DOT(q4,e4) DOT(q5,e5) DOT(q6,e6) DOT(q7,e7)
    #undef DOT

    // lanes 0..7 own rows s0..s0+7
    float e = e0;
    e = (lane == 1) ? e1 : e;  e = (lane == 2) ? e2 : e;
    e = (lane == 3) ? e3 : e;  e = (lane == 4) ? e4 : e;
    e = (lane == 5) ? e5 : e;  e = (lane == 6) ? e6 : e;
    e = (lane == 7) ? e7 : e;
    double ps = 0.0;
    if (lane < 8) {
        const float f = e * 1.4426950408889634f;   // e / ln(2)
        const float n = rintf(f);
        const float m = exp2f(f - n);              // v_exp_f32
        const long long eb = ((long long)(1023 + (int)n)) << 52;
        ps = (double)m * __longlong_as_double(eb); // exact 2^n scale
        ws_p[s0 + lane] = ps;                      // contiguous 64B/wave
    }
    double p = ps;                                 // 8-lane group sum
    p += __shfl_xor(p, 1, 64);
    p += __shfl_xor(p, 2, 64);
    p += __shfl_xor(p, 4, 64);
    if (lane == 0) s_lds[wid] = p;
    __syncthreads();
    if (t == 0) {
        double S = 0.0;
        #pragma unroll
        for (int w = 0; w < K2T / 64; ++w) S += s_lds[w];
        ws_sum[b] = S;
    }
}

// ---- K3: redundant global-sum reduce (4KB, L2), normalize, write out.
__global__ __launch_bounds__(256) void k3_norm(const double* __restrict__ ws_p,
                                               const double* __restrict__ ws_sum,
                                               float* __restrict__ out) {
    __shared__ double s_lds[4];
    __shared__ double inv_lds;
    const int t = threadIdx.x, b = blockIdx.x;
    const int lane = t & 63, wid = t >> 6;

    double a = ws_sum[t] + ws_sum[t + 256];        // K2B=512 -> 2 per thread
    a = wave_sum_d(a);
    if (lane == 0) s_lds[wid] = a;
    __syncthreads();
    if (t == 0) inv_lds = 1.0 / ((s_lds[0] + s_lds[1]) + (s_lds[2] + s_lds[3]));
    __syncthreads();

    const int i = b * 256 + t;
    out[i] = (float)(ws_p[i] * inv_lds);
}

extern "C" void kernel_launch(void* const* d_in, const int* in_sizes, int n_in,
                              void* d_out, int out_size, void* d_ws, size_t ws_size,
                              hipStream_t stream) {
    const float* hidden = (const float*)d_in[0];   // [H]
    const float* enc    = (const float*)d_in[1];   // [SEQ, DENC]
    const float* W      = (const float*)d_in[2];   // [H, 200]
    float* out = (float*)d_out;

    float*  ws_v   = (float*)d_ws;                 // [K1B*DENC]
    double* ws_p   = (double*)(ws_v + K1B * DENC); // [SEQ]
    double* ws_sum = ws_p + SEQ;                   // [K2B]

    k1_proj  <<<K1B, K1T, 0, stream>>>(W, hidden, ws_v);
    k2_energy<<<K2B, K2T, 0, stream>>>(enc, ws_v, ws_p, ws_sum);
    k3_norm  <<<K3B, 256, 0, stream>>>(ws_p, ws_sum, out);
}

// Round 12
// 19.787 us; speedup vs baseline: 1.0326x; 1.0326x over previous
//
#include <hip/hip_runtime.h>
#include <math.h>

#define SEQ   32768
#define DENC  200
#define NH    8192

#define K1B    256
#define K1T    256
#define K1ROWS (NH / K1B)                // 32 rows per block

#define K2B    512
#define K2T    512                       // 8 waves
#define K2ROWS (SEQ / K2B)               // 64 rows per block
#define RPW    8                         // rows per wave

#define K3B    (SEQ / 256)               // 128

// ws layout: float ws_v[DENC][K1B] (transposed banks, plain stores);
// float vfin[DENC]; double ws_p[SEQ]; double ws_sum[K2B].
// Everything fully rewritten every launch; no zeroing, no atomics,
// no cross-block communication inside any kernel (G16).

__device__ __forceinline__ double wave_sum_d(double x) {
    #pragma unroll
    for (int off = 32; off; off >>= 1) x += __shfl_xor(x, off, 64);
    return x;
}
__device__ __forceinline__ float wave_sum(float x) {
    #pragma unroll
    for (int off = 32; off; off >>= 1) x += __shfl_xor(x, off, 64);
    return x;
}

// ---- K1: full-machine W pull; transposed bank store ws_v[d][b].
__global__ __launch_bounds__(K1T) void k1_proj(const float* __restrict__ W,
                                               const float* __restrict__ hidden,
                                               float* __restrict__ ws_v) {
    const int t = threadIdx.x, b = blockIdx.x;
    const int h0 = b * K1ROWS;
    if (t < DENC) {
        float acc = 0.f;
        #pragma unroll 8
        for (int i = 0; i < K1ROWS; ++i)
            acc = fmaf(W[(size_t)(h0 + i) * DENC + t], hidden[h0 + i], acc);
        ws_v[(size_t)t * K1B + b] = acc;   // [d][bank]
    }
}

// ---- K1.5: one wave per d; coalesced float4 row read; wave-reduce.
__global__ __launch_bounds__(64) void k15_reduce(const float* __restrict__ ws_v,
                                                 float* __restrict__ vfin) {
    const int d = blockIdx.x, l = threadIdx.x;
    const float4 f = *(const float4*)(ws_v + (size_t)d * K1B + 4 * l);
    float a = (f.x + f.y) + (f.z + f.w);
    a = wave_sum(a);
    if (l == 0) vfin[d] = a;
}

// ---- K2: energies from register-preloaded enc rows; v is one 800B read;
// exp via v_exp_f32 + exponent-bit double scale (no max pass; |e| << 709).
__global__ __launch_bounds__(K2T) void k2_energy(const float* __restrict__ enc,
                                                 const float* __restrict__ vfin,
                                                 double* __restrict__ ws_p,
                                                 double* __restrict__ ws_sum) {
    __shared__ float  v_lds[DENC];
    __shared__ double s_lds[K2T / 64];
    const int t = threadIdx.x, b = blockIdx.x;
    const int lane = t & 63, wid = t >> 6;
    const bool act = (lane < 50);

    // enc loads first: they are the long pole
    const int s0 = b * K2ROWS + wid * RPW;
    const float* ebase = enc + (size_t)s0 * DENC + lane * 4;
    float4 q0 = *(const float4*)(act ? ebase + 0*DENC : enc);
    float4 q1 = *(const float4*)(act ? ebase + 1*DENC : enc);
    float4 q2 = *(const float4*)(act ? ebase + 2*DENC : enc);
    float4 q3 = *(const float4*)(act ? ebase + 3*DENC : enc);
    float4 q4 = *(const float4*)(act ? ebase + 4*DENC : enc);
    float4 q5 = *(const float4*)(act ? ebase + 5*DENC : enc);
    float4 q6 = *(const float4*)(act ? ebase + 6*DENC : enc);
    float4 q7 = *(const float4*)(act ? ebase + 7*DENC : enc);

    if (t < DENC) v_lds[t] = vfin[t];      // 800 B, L2-resident
    __syncthreads();

    float4 v4 = make_float4(0.f, 0.f, 0.f, 0.f);
    if (act) v4 = *(const float4*)(v_lds + lane * 4);

    float e0,e1,e2,e3,e4,e5,e6,e7;
    #define DOT(qi, ei) { \
        float d = act ? (qi.x*v4.x + qi.y*v4.y + qi.z*v4.z + qi.w*v4.w) : 0.f; \
        ei = wave_sum(d); }
    DOT(q0,e0) DOT(q1,e1) DOT(q2,e2) DOT(q3,e3)
    DOT(q4,e4) DOT(q5,e5) DOT(q6,e6) DOT(q7,e7)
    #undef DOT

    // lanes 0..7 own rows s0..s0+7
    float e = e0;
    e = (lane == 1) ? e1 : e;  e = (lane == 2) ? e2 : e;
    e = (lane == 3) ? e3 : e;  e = (lane == 4) ? e4 : e;
    e = (lane == 5) ? e5 : e;  e = (lane == 6) ? e6 : e;
    e = (lane == 7) ? e7 : e;
    double ps = 0.0;
    if (lane < 8) {
        const float f = e * 1.4426950408889634f;   // e / ln(2)
        const float n = rintf(f);
        const float m = exp2f(f - n);              // v_exp_f32
        const long long eb = ((long long)(1023 + (int)n)) << 52;
        ps = (double)m * __longlong_as_double(eb); // exact 2^n scale
        ws_p[s0 + lane] = ps;                      // contiguous 64B/wave
    }
    double p = ps;                                 // 8-lane group sum
    p += __shfl_xor(p, 1, 64);
    p += __shfl_xor(p, 2, 64);
    p += __shfl_xor(p, 4, 64);
    if (lane == 0) s_lds[wid] = p;
    __syncthreads();
    if (t == 0) {
        double S = 0.0;
        #pragma unroll
        for (int w = 0; w < K2T / 64; ++w) S += s_lds[w];
        ws_sum[b] = S;
    }
}

// ---- K3: redundant global-sum reduce (4KB, L2), normalize, write out.
__global__ __launch_bounds__(256) void k3_norm(const double* __restrict__ ws_p,
                                               const double* __restrict__ ws_sum,
                                               float* __restrict__ out) {
    __shared__ double s_lds[4];
    __shared__ double inv_lds;
    const int t = threadIdx.x, b = blockIdx.x;
    const int lane = t & 63, wid = t >> 6;

    double a = ws_sum[t] + ws_sum[t + 256];        // K2B=512 -> 2 per thread
    a = wave_sum_d(a);
    if (lane == 0) s_lds[wid] = a;
    __syncthreads();
    if (t == 0) inv_lds = 1.0 / ((s_lds[0] + s_lds[1]) + (s_lds[2] + s_lds[3]));
    __syncthreads();

    const int i = b * 256 + t;
    out[i] = (float)(ws_p[i] * inv_lds);
}

extern "C" void kernel_launch(void* const* d_in, const int* in_sizes, int n_in,
                              void* d_out, int out_size, void* d_ws, size_t ws_size,
                              hipStream_t stream) {
    const float* hidden = (const float*)d_in[0];   // [H]
    const float* enc    = (const float*)d_in[1];   // [SEQ, DENC]
    const float* W      = (const float*)d_in[2];   // [H, 200]
    float* out = (float*)d_out;

    float*  ws_v   = (float*)d_ws;                 // [DENC*K1B]
    float*  vfin   = ws_v + (size_t)DENC * K1B;    // [DENC]
    double* ws_p   = (double*)(vfin + DENC + 56);  // [SEQ] (8B-aligned, padded)
    double* ws_sum = ws_p + SEQ;                   // [K2B]

    k1_proj   <<<K1B,  K1T, 0, stream>>>(W, hidden, ws_v);
    k15_reduce<<<DENC, 64,  0, stream>>>(ws_v, vfin);
    k2_energy <<<K2B,  K2T, 0, stream>>>(enc, vfin, ws_p, ws_sum);
    k3_norm   <<<K3B,  256, 0, stream>>>(ws_p, ws_sum, out);
}